// Round 7
// baseline (122.181 us; speedup 1.0000x reference)
//
#include <hip/hip_runtime.h>

// IMM loss: G=8192 groups of M=16 particles, D=64 dims, fp32.
// terms = Lap(x,x)+Lap(y,y)-2*Lap(x,y), Lap = exp(-ws[j]*max(||a-b||,EPS)/D).
//
// R7: Gram-trick main loop. d^2(a,b) = |a|^2+|b|^2-2<a,b>, so the inner loop
// accumulates dot products (1 fused v_fmac_f32_dpp per single-use rotation)
// instead of sub+fma difference chains: 42 inst/dim vs R6's 64. Norms (sxx,
// syy) accumulated once per dim. Epilogue reconstructs d^2 from red4'd dots
// + DPP-rotated norms, with fmax(d2,0) guarding cancellation before sqrt.
//
// Lane map (R5/R6, coalesced): one wave per group; lane=q*16+j holds dims
// [16q,16q+16) of particle j -> wave covers one contiguous 4 KB block per
// tensor. Partner (j+o)&15 has same q -> DPP row_ror works. Inverted loop
// nest kept from R6 (each loaded value feeds all 34 persistent accumulators
// at its single load site -> nothing for the compiler to re-materialize).

#define EPS_D 0.006f

// Rotate right within each 16-lane row by O (compile-time 1..15):
// lane q*16+j receives lane q*16+((j+O)&15). Verified exact (R2-R6 absmax 0.0).
#define ROT(v, O) __int_as_float(__builtin_amdgcn_update_dpp(              \
        0, __float_as_int(v), 0x120 + (O), 0xF, 0xF, false))

// Sum the 4 q-row partials (lanes j, j+16, j+32, j+48): all lanes get total.
__device__ __forceinline__ float red4(float p) {
    p += __shfl_xor(p, 16, 64);
    p += __shfl_xor(p, 32, 64);
    return p;
}

// Per-dim accumulator updates. ROT(xv,O) single-use -> fmac_dpp fusion;
// ROT(yv,O) double-use in full offsets -> one v_mov_dpp + 2 fmac.
#define UPD_FULL(O) {                                                      \
    axx[(O)-1] = fmaf(ROT(xv,(O)), xv, axx[(O)-1]);                        \
    float yr = ROT(yv,(O));                                                \
    ayy[(O)-1] = fmaf(yr, yv, ayy[(O)-1]);                                 \
    axy[(O)]   = fmaf(yr, xv, axy[(O)]); }

#define UPD_XY(O)                                                          \
    axy[(O)] = fmaf(ROT(yv,(O)), xv, axy[(O)]);

#define DIM_STEP(XV, YV) {                                                 \
    const float xv = (XV), yv = (YV);                                      \
    sxx    = fmaf(xv, xv, sxx);                                            \
    syy    = fmaf(yv, yv, syy);                                            \
    axy[0] = fmaf(xv, yv, axy[0]);                                         \
    UPD_FULL(1) UPD_FULL(2) UPD_FULL(3) UPD_FULL(4)                        \
    UPD_FULL(5) UPD_FULL(6) UPD_FULL(7) UPD_FULL(8)                        \
    UPD_XY(9) UPD_XY(10) UPD_XY(11) UPD_XY(12)                             \
    UPD_XY(13) UPD_XY(14) UPD_XY(15) }

__global__ __launch_bounds__(256, 2)   // cap 256: avoid R3's forced-spill tier
void imm_loss_kernel(const float* __restrict__ ys_t,
                     const float* __restrict__ ys_r,
                     const float* __restrict__ w_scale,
                     const float* __restrict__ time_w,
                     float* __restrict__ partials)
{
    const int tid  = threadIdx.x;
    const int lane = tid & 63;
    const int wave = tid >> 6;
    const int q    = lane >> 4;          // dim slice [16q, 16q+16)
    const int j    = lane & 15;          // particle index
    const int g    = blockIdx.x * 4 + wave;   // group id

    const size_t base = (size_t)g * 1024 + j * 64 + q * 16;
    const float4* xp = reinterpret_cast<const float4*>(ys_t + base);
    const float4* yp = reinterpret_cast<const float4*>(ys_r + base);

    // Gram accumulators (persistent; partial over this lane's 16 dims).
    float sxx = 0.f, syy = 0.f;          // |x_j|^2, |y_j|^2 partials
    float axx[8], ayy[8];                // <x_j, x_{j+o}>, <y_j, y_{j+o}>, o=1..8
    float axy[16];                       // <x_j, y_{j+o}>, o=0..15
    #pragma unroll
    for (int i = 0; i < 8; ++i) { axx[i] = 0.f; ayy[i] = 0.f; }
    #pragma unroll
    for (int i = 0; i < 16; ++i) axy[i] = 0.f;

    // Stream 16 dims as 4 float4 pairs; each value consumed fully on arrival.
    #pragma unroll
    for (int t = 0; t < 4; ++t) {
        float4 xv4 = xp[t];
        float4 yv4 = yp[t];
        DIM_STEP(xv4.x, yv4.x)
        DIM_STEP(xv4.y, yv4.y)
        DIM_STEP(xv4.z, yv4.z)
        DIM_STEP(xv4.w, yv4.w)
    }

    const float s_j = w_scale[g * 16 + j] * (1.0f / 64.0f);  // ws[j]/D
    const float tw  = time_w[g * 16];                        // per-group weight

    const float n2x = red4(sxx);         // |x_j|^2 (full, all lanes)
    const float n2y = red4(syy);         // |y_j|^2

    // xx + yy diagonals (d=0 clamps to EPS).
    float acc = 2.0f * __expf(-s_j * EPS_D);

    // xy offset 0.
    {
        float d2 = fmaxf(n2x + n2y - 2.0f * red4(axy[0]), 0.f);
        acc -= 2.0f * __expf(-s_j * fmaxf(sqrtf(d2), EPS_D));
    }

    // Full pair offsets 1..8: xx & yy via symmetry (ordered (j,k) uses s_j,
    // (k,j) uses s_k; o=8 hit from both endpoints -> weight 0.5) + xy.
#define EPI_FULL(O, W) {                                                   \
        float pxx = red4(axx[(O)-1]);                                      \
        float pyy = red4(ayy[(O)-1]);                                      \
        float pxy = red4(axy[(O)]);                                        \
        const float nxk = ROT(n2x, (O));                                   \
        const float nyk = ROT(n2y, (O));                                   \
        const float s_k = ROT(s_j, (O));                                   \
        float d2x = fmaxf(n2x + nxk - 2.0f * pxx, 0.f);                    \
        float d2y = fmaxf(n2y + nyk - 2.0f * pyy, 0.f);                    \
        float d2z = fmaxf(n2x + nyk - 2.0f * pxy, 0.f);                    \
        const float ddx = fmaxf(sqrtf(d2x), EPS_D);                        \
        const float ddy = fmaxf(sqrtf(d2y), EPS_D);                        \
        const float ddz = fmaxf(sqrtf(d2z), EPS_D);                        \
        acc += (W) * (__expf(-s_j * ddx) + __expf(-s_k * ddx));            \
        acc += (W) * (__expf(-s_j * ddy) + __expf(-s_k * ddy));            \
        acc -= 2.0f * __expf(-s_j * ddz); }

#define EPI_XY(O) {                                                        \
        float d2 = fmaxf(n2x + ROT(n2y,(O)) - 2.0f * red4(axy[(O)]), 0.f); \
        acc -= 2.0f * __expf(-s_j * fmaxf(sqrtf(d2), EPS_D)); }

    EPI_FULL(1, 1.0f) EPI_FULL(2, 1.0f) EPI_FULL(3, 1.0f) EPI_FULL(4, 1.0f)
    EPI_FULL(5, 1.0f) EPI_FULL(6, 1.0f) EPI_FULL(7, 1.0f) EPI_FULL(8, 0.5f)
    EPI_XY(9) EPI_XY(10) EPI_XY(11) EPI_XY(12)
    EPI_XY(13) EPI_XY(14) EPI_XY(15)

    // acc replicated across 4 q-rows; extra x4 folded into inv_scale.
    float val = acc * tw;
    #pragma unroll
    for (int off = 32; off; off >>= 1)
        val += __shfl_xor(val, off, 64);

    __shared__ float smem[4];
    if (lane == 0) smem[wave] = val;
    __syncthreads();
    if (tid == 0)
        partials[blockIdx.x] = smem[0] + smem[1] + smem[2] + smem[3];
}

__global__ void imm_reduce_kernel(const float* __restrict__ part, int n,
                                  float inv_scale, float* __restrict__ out)
{
    const int tid = threadIdx.x;
    float v = 0.f;
    for (int i = tid; i < n; i += 256) v += part[i];
    #pragma unroll
    for (int off = 32; off; off >>= 1) v += __shfl_xor(v, off, 64);
    __shared__ float s[4];
    if ((tid & 63) == 0) s[tid >> 6] = v;
    __syncthreads();
    if (tid == 0) out[0] = (s[0] + s[1] + s[2] + s[3]) * inv_scale;
}

extern "C" void kernel_launch(void* const* d_in, const int* in_sizes, int n_in,
                              void* d_out, int out_size, void* d_ws, size_t ws_size,
                              hipStream_t stream)
{
    const float* ys_t = (const float*)d_in[0];
    const float* ys_r = (const float*)d_in[1];
    const float* wsc  = (const float*)d_in[2];
    const float* twp  = (const float*)d_in[3];
    float* out      = (float*)d_out;
    float* partials = (float*)d_ws;

    const int B = in_sizes[2];      // 131072
    const int G = B / 16;           // 8192 groups
    const int blocks = G / 4;       // 1 group per wave, 4 waves per block

    imm_loss_kernel<<<blocks, 256, 0, stream>>>(ys_t, ys_r, wsc, twp, partials);

    // 1/(M*M*G) with the extra /4 for q-row replication of acc.
    const float inv_scale = 1.0f / (4.0f * 256.0f * (float)G);
    imm_reduce_kernel<<<1, 256, 0, stream>>>(partials, blocks, inv_scale, out);
}